// Round 1
// baseline (791.787 us; speedup 1.0000x reference)
//
#include <hip/hip_runtime.h>
#include <stdint.h>

// GridEncoder (instant-ngp hash grid), D=3, L=16, C=2, H=16, PLS=2, log2_hash=19.
// All levels resolve to gridtype=hash (since (res+1)^3 > hsize at every level),
// and every hsize is a power of two -> modulo becomes AND with mask.
// Numerics: pos = x*scale + 0.5 must NOT be fma-contracted (numpy ref does
// separate mul/add; at level 15 pos ~ 5e5 so 1 ULP changes f by ~0.03).

#define NLEV 16

__global__ __launch_bounds__(256) void grid_encode_kernel(
    const float* __restrict__ inp,   // [B,3]
    const float* __restrict__ emb,   // [total_rows, 2]
    float* __restrict__ out,         // [B, 32]
    int B)
{
    const int b = blockIdx.x * blockDim.x + threadIdx.x;
    if (b >= B) return;

    // per-level static tables (computed from the reference's build_offsets)
    const uint32_t kOff[NLEV] = {
        0u, 4096u, 36864u, 299008u, 823296u, 1347584u, 1871872u, 2396160u,
        2920448u, 3444736u, 3969024u, 4493312u, 5017600u, 5541888u,
        6066176u, 6590464u };
    const uint32_t kMask[NLEV] = {
        4095u, 32767u, 262143u, 524287u, 524287u, 524287u, 524287u, 524287u,
        524287u, 524287u, 524287u, 524287u, 524287u, 524287u, 524287u, 524287u };
    const float kScale[NLEV] = {
        15.f, 31.f, 63.f, 127.f, 255.f, 511.f, 1023.f, 2047.f,
        4095.f, 8191.f, 16383.f, 32767.f, 65535.f, 131071.f, 262143.f, 524287.f };

    constexpr uint32_t P1 = 2654435761u, P2 = 805459861u;

    const float ix = inp[3 * b + 0];
    const float iy = inp[3 * b + 1];
    const float iz = inp[3 * b + 2];
    // (in + 1) / 2 : division by 2 is exact, multiply-by-0.5 identical
    const float x = (ix + 1.0f) * 0.5f;
    const float y = (iy + 1.0f) * 0.5f;
    const float z = (iz + 1.0f) * 0.5f;

    const float2* __restrict__ etab = (const float2*)emb;

    float res[2 * NLEV];

    #pragma unroll
    for (int l = 0; l < NLEV; ++l) {
        const float   scale = kScale[l];
        const uint32_t mask = kMask[l];
        const uint32_t off  = kOff[l];

        // forbid fma contraction: match numpy's separate mul+add rounding
        const float px = __fadd_rn(__fmul_rn(x, scale), 0.5f);
        const float py = __fadd_rn(__fmul_rn(y, scale), 0.5f);
        const float pz = __fadd_rn(__fmul_rn(z, scale), 0.5f);
        const float fx0 = floorf(px), fy0 = floorf(py), fz0 = floorf(pz);
        const uint32_t X0 = (uint32_t)fx0;
        const uint32_t Y0 = (uint32_t)fy0;
        const uint32_t Z0 = (uint32_t)fz0;
        const float fx = px - fx0, fy = py - fy0, fz = pz - fz0;

        // incremental hash terms (PRIMES[0] == 1)
        const uint32_t hx0 = X0,        hx1 = X0 + 1u;
        const uint32_t hy0 = Y0 * P1,   hy1 = hy0 + P1;
        const uint32_t hz0 = Z0 * P2,   hz1 = hz0 + P2;

        const uint32_t r0 = ((hx0 ^ hy0 ^ hz0) & mask) + off;
        const uint32_t r1 = ((hx1 ^ hy0 ^ hz0) & mask) + off;
        const uint32_t r2 = ((hx0 ^ hy1 ^ hz0) & mask) + off;
        const uint32_t r3 = ((hx1 ^ hy1 ^ hz0) & mask) + off;
        const uint32_t r4 = ((hx0 ^ hy0 ^ hz1) & mask) + off;
        const uint32_t r5 = ((hx1 ^ hy0 ^ hz1) & mask) + off;
        const uint32_t r6 = ((hx0 ^ hy1 ^ hz1) & mask) + off;
        const uint32_t r7 = ((hx1 ^ hy1 ^ hz1) & mask) + off;

        // issue all 8 gathers before consuming (latency hiding / MLP)
        const float2 e0 = etab[r0];
        const float2 e1 = etab[r1];
        const float2 e2 = etab[r2];
        const float2 e3 = etab[r3];
        const float2 e4 = etab[r4];
        const float2 e5 = etab[r5];
        const float2 e6 = etab[r6];
        const float2 e7 = etab[r7];

        const float wx1 = fx, wx0 = 1.0f - fx;
        const float wy1 = fy, wy0 = 1.0f - fy;
        const float wz1 = fz, wz0 = 1.0f - fz;
        const float wy0z0 = wy0 * wz0, wy1z0 = wy1 * wz0;
        const float wy0z1 = wy0 * wz1, wy1z1 = wy1 * wz1;

        float a0 = 0.0f, a1 = 0.0f;
        float w;
        w = wx0 * wy0z0; a0 = fmaf(w, e0.x, a0); a1 = fmaf(w, e0.y, a1);
        w = wx1 * wy0z0; a0 = fmaf(w, e1.x, a0); a1 = fmaf(w, e1.y, a1);
        w = wx0 * wy1z0; a0 = fmaf(w, e2.x, a0); a1 = fmaf(w, e2.y, a1);
        w = wx1 * wy1z0; a0 = fmaf(w, e3.x, a0); a1 = fmaf(w, e3.y, a1);
        w = wx0 * wy0z1; a0 = fmaf(w, e4.x, a0); a1 = fmaf(w, e4.y, a1);
        w = wx1 * wy0z1; a0 = fmaf(w, e5.x, a0); a1 = fmaf(w, e5.y, a1);
        w = wx0 * wy1z1; a0 = fmaf(w, e6.x, a0); a1 = fmaf(w, e6.y, a1);
        w = wx1 * wy1z1; a0 = fmaf(w, e7.x, a0); a1 = fmaf(w, e7.y, a1);

        res[2 * l + 0] = a0;
        res[2 * l + 1] = a1;
    }

    // 32 contiguous floats per point -> 8 x float4 stores
    float4* __restrict__ o4 = (float4*)(out + (size_t)b * (2 * NLEV));
    #pragma unroll
    for (int k = 0; k < 8; ++k) {
        o4[k] = make_float4(res[4 * k + 0], res[4 * k + 1],
                            res[4 * k + 2], res[4 * k + 3]);
    }
}

extern "C" void kernel_launch(void* const* d_in, const int* in_sizes, int n_in,
                              void* d_out, int out_size, void* d_ws, size_t ws_size,
                              hipStream_t stream) {
    const float* inp = (const float*)d_in[0];   // [B,3] float32
    const float* emb = (const float*)d_in[1];   // [total_rows,2] float32
    float* out = (float*)d_out;                 // [B,32] float32

    const int B = in_sizes[0] / 3;
    const int block = 256;
    const int grid = (B + block - 1) / block;
    grid_encode_kernel<<<grid, block, 0, stream>>>(inp, emb, out, B);
}

// Round 2
// 715.469 us; speedup vs baseline: 1.1067x; 1.1067x over previous
//
#include <hip/hip_runtime.h>
#include <stdint.h>

// GridEncoder (instant-ngp hash grid), D=3, L=16, C=2, H=16, PLS=2, log2_hash=19.
// Round 2: level-major execution. Each per-level kernel's table slice is <=4MB
// (= per-XCD L2), so the 8M random gathers/level become L2 hits instead of
// Infinity-Cache round trips (round 1: FETCH_SIZE=2.6GB, 770us, latency-bound).
// Per-level results go to a level-major scratch slab (coalesced 8B writes),
// then one interleave pass produces the [B, L*C] layout with float4 stores.
// Numerics: identical per-level arithmetic to the round-1 passing kernel
// (no fma contraction of x*scale+0.5).

#define NLEV 16

static const uint32_t kOffH[NLEV] = {
    0u, 4096u, 36864u, 299008u, 823296u, 1347584u, 1871872u, 2396160u,
    2920448u, 3444736u, 3969024u, 4493312u, 5017600u, 5541888u,
    6066176u, 6590464u };
static const uint32_t kMaskH[NLEV] = {
    4095u, 32767u, 262143u, 524287u, 524287u, 524287u, 524287u, 524287u,
    524287u, 524287u, 524287u, 524287u, 524287u, 524287u, 524287u, 524287u };
static const float kScaleH[NLEV] = {
    15.f, 31.f, 63.f, 127.f, 255.f, 511.f, 1023.f, 2047.f,
    4095.f, 8191.f, 16383.f, 32767.f, 65535.f, 131071.f, 262143.f, 524287.f };

__device__ __forceinline__ void encode_point(
    float x, float y, float z, float scale, uint32_t mask, uint32_t off,
    const float2* __restrict__ etab, uint32_t rows[8], float ws[8])
{
    constexpr uint32_t P1 = 2654435761u, P2 = 805459861u;
    const float px = __fadd_rn(__fmul_rn(x, scale), 0.5f);
    const float py = __fadd_rn(__fmul_rn(y, scale), 0.5f);
    const float pz = __fadd_rn(__fmul_rn(z, scale), 0.5f);
    const float fx0 = floorf(px), fy0 = floorf(py), fz0 = floorf(pz);
    const uint32_t X0 = (uint32_t)fx0;
    const uint32_t Y0 = (uint32_t)fy0;
    const uint32_t Z0 = (uint32_t)fz0;
    const float fx = px - fx0, fy = py - fy0, fz = pz - fz0;

    const uint32_t hx0 = X0,      hx1 = X0 + 1u;
    const uint32_t hy0 = Y0 * P1, hy1 = hy0 + P1;
    const uint32_t hz0 = Z0 * P2, hz1 = hz0 + P2;

    rows[0] = ((hx0 ^ hy0 ^ hz0) & mask) + off;
    rows[1] = ((hx1 ^ hy0 ^ hz0) & mask) + off;
    rows[2] = ((hx0 ^ hy1 ^ hz0) & mask) + off;
    rows[3] = ((hx1 ^ hy1 ^ hz0) & mask) + off;
    rows[4] = ((hx0 ^ hy0 ^ hz1) & mask) + off;
    rows[5] = ((hx1 ^ hy0 ^ hz1) & mask) + off;
    rows[6] = ((hx0 ^ hy1 ^ hz1) & mask) + off;
    rows[7] = ((hx1 ^ hy1 ^ hz1) & mask) + off;

    const float wx1 = fx, wx0 = 1.0f - fx;
    const float wy1 = fy, wy0 = 1.0f - fy;
    const float wz1 = fz, wz0 = 1.0f - fz;
    const float wy0z0 = wy0 * wz0, wy1z0 = wy1 * wz0;
    const float wy0z1 = wy0 * wz1, wy1z1 = wy1 * wz1;
    ws[0] = wx0 * wy0z0; ws[1] = wx1 * wy0z0;
    ws[2] = wx0 * wy1z0; ws[3] = wx1 * wy1z0;
    ws[4] = wx0 * wy0z1; ws[5] = wx1 * wy0z1;
    ws[6] = wx0 * wy1z1; ws[7] = wx1 * wy1z1;
}

// one level, two points per thread (points t and t + B/2)
__global__ __launch_bounds__(256, 6) void level_kernel(
    const float* __restrict__ inp,   // [B,3]
    const float2* __restrict__ etab, // [total_rows]
    float2* __restrict__ slab,       // [B] for this level
    int B, float scale, uint32_t mask, uint32_t off)
{
    const int t = blockIdx.x * blockDim.x + threadIdx.x;
    const int half = B >> 1;
    if (t >= half) return;
    const int b0 = t, b1 = t + half;

    const float x0 = (inp[3 * b0 + 0] + 1.0f) * 0.5f;
    const float y0 = (inp[3 * b0 + 1] + 1.0f) * 0.5f;
    const float z0 = (inp[3 * b0 + 2] + 1.0f) * 0.5f;
    const float x1 = (inp[3 * b1 + 0] + 1.0f) * 0.5f;
    const float y1 = (inp[3 * b1 + 1] + 1.0f) * 0.5f;
    const float z1 = (inp[3 * b1 + 2] + 1.0f) * 0.5f;

    uint32_t r0[8], r1[8];
    float w0[8], w1[8];
    encode_point(x0, y0, z0, scale, mask, off, etab, r0, w0);
    encode_point(x1, y1, z1, scale, mask, off, etab, r1, w1);

    // issue all 16 gathers before consuming
    float2 e0[8], e1[8];
    #pragma unroll
    for (int c = 0; c < 8; ++c) e0[c] = etab[r0[c]];
    #pragma unroll
    for (int c = 0; c < 8; ++c) e1[c] = etab[r1[c]];

    float a0x = 0.f, a0y = 0.f, a1x = 0.f, a1y = 0.f;
    #pragma unroll
    for (int c = 0; c < 8; ++c) {
        a0x = fmaf(w0[c], e0[c].x, a0x);
        a0y = fmaf(w0[c], e0[c].y, a0y);
        a1x = fmaf(w1[c], e1[c].x, a1x);
        a1y = fmaf(w1[c], e1[c].y, a1y);
    }
    slab[b0] = make_float2(a0x, a0y);
    slab[b1] = make_float2(a1x, a1y);
}

// ws [L][B] float2 (level-major)  ->  out [B][8] float4 (level-interleaved)
__global__ __launch_bounds__(256) void interleave_kernel(
    const float2* __restrict__ ws, float4* __restrict__ out, int B)
{
    const int b = blockIdx.x * blockDim.x + threadIdx.x;
    if (b >= B) return;
    float2 v[NLEV];
    #pragma unroll
    for (int l = 0; l < NLEV; ++l) v[l] = ws[(size_t)l * B + b];
    float4* o = out + (size_t)b * 8;
    #pragma unroll
    for (int k = 0; k < 8; ++k)
        o[k] = make_float4(v[2 * k].x, v[2 * k].y, v[2 * k + 1].x, v[2 * k + 1].y);
}

// ---------------- fallback: round-1 flat kernel (proven correct) -----------
__global__ __launch_bounds__(256) void grid_encode_flat(
    const float* __restrict__ inp, const float* __restrict__ emb,
    float* __restrict__ out, int B)
{
    const int b = blockIdx.x * blockDim.x + threadIdx.x;
    if (b >= B) return;
    const uint32_t kOff[NLEV] = {
        0u, 4096u, 36864u, 299008u, 823296u, 1347584u, 1871872u, 2396160u,
        2920448u, 3444736u, 3969024u, 4493312u, 5017600u, 5541888u,
        6066176u, 6590464u };
    const uint32_t kMask[NLEV] = {
        4095u, 32767u, 262143u, 524287u, 524287u, 524287u, 524287u, 524287u,
        524287u, 524287u, 524287u, 524287u, 524287u, 524287u, 524287u, 524287u };
    const float kScale[NLEV] = {
        15.f, 31.f, 63.f, 127.f, 255.f, 511.f, 1023.f, 2047.f,
        4095.f, 8191.f, 16383.f, 32767.f, 65535.f, 131071.f, 262143.f, 524287.f };

    const float x = (inp[3 * b + 0] + 1.0f) * 0.5f;
    const float y = (inp[3 * b + 1] + 1.0f) * 0.5f;
    const float z = (inp[3 * b + 2] + 1.0f) * 0.5f;
    const float2* etab = (const float2*)emb;
    float res[2 * NLEV];
    #pragma unroll
    for (int l = 0; l < NLEV; ++l) {
        uint32_t rows[8]; float wts[8];
        encode_point(x, y, z, kScale[l], kMask[l], kOff[l], etab, rows, wts);
        float2 e[8];
        #pragma unroll
        for (int c = 0; c < 8; ++c) e[c] = etab[rows[c]];
        float ax = 0.f, ay = 0.f;
        #pragma unroll
        for (int c = 0; c < 8; ++c) { ax = fmaf(wts[c], e[c].x, ax); ay = fmaf(wts[c], e[c].y, ay); }
        res[2 * l + 0] = ax; res[2 * l + 1] = ay;
    }
    float4* o4 = (float4*)(out + (size_t)b * (2 * NLEV));
    #pragma unroll
    for (int k = 0; k < 8; ++k)
        o4[k] = make_float4(res[4 * k + 0], res[4 * k + 1], res[4 * k + 2], res[4 * k + 3]);
}

extern "C" void kernel_launch(void* const* d_in, const int* in_sizes, int n_in,
                              void* d_out, int out_size, void* d_ws, size_t ws_size,
                              hipStream_t stream) {
    const float* inp = (const float*)d_in[0];   // [B,3] float32
    const float* emb = (const float*)d_in[1];   // [total_rows,2] float32
    float* out = (float*)d_out;                 // [B,32] float32
    const int B = in_sizes[0] / 3;

    const size_t need = (size_t)B * NLEV * 2 * sizeof(float);
    if (ws_size >= need) {
        float2* ws = (float2*)d_ws;
        const float2* etab = (const float2*)emb;
        const int half = B >> 1;
        const int blkL = (half + 255) / 256;
        for (int l = 0; l < NLEV; ++l) {
            level_kernel<<<blkL, 256, 0, stream>>>(
                inp, etab, ws + (size_t)l * B, B, kScaleH[l], kMaskH[l], kOffH[l]);
        }
        const int blkI = (B + 255) / 256;
        interleave_kernel<<<blkI, 256, 0, stream>>>(ws, (float4*)out, B);
    } else {
        const int blk = (B + 255) / 256;
        grid_encode_flat<<<blk, 256, 0, stream>>>(inp, emb, out, B);
    }
}

// Round 3
// 537.446 us; speedup vs baseline: 1.4732x; 1.3312x over previous
//
#include <hip/hip_runtime.h>
#include <stdint.h>

// GridEncoder (instant-ngp hash grid), D=3, L=16, C=2, H=16, PLS=2, log2_hash=19.
// Round 3:
//  - fused level-major kernel: blockIdx.y = level (one dispatch instead of 16;
//    x-major dispatch order keeps per-level table slices (<=4MB = per-XCD L2)
//    resident while removing 15 launch/tail-drain bubbles ~6us each).
//  - interleave rewritten chunk-per-thread: each thread writes exactly one
//    float4 of out (fully coalesced; round-2 version had lane-stride-128B
//    stores -> 484MB HBM writes, 3.6x amplification, 160us).
// Numerics: identical per-level arithmetic to the round-1/2 passing kernels
// (no fma contraction of x*scale+0.5).

#define NLEV 16

static const uint32_t kOffH[NLEV] = {
    0u, 4096u, 36864u, 299008u, 823296u, 1347584u, 1871872u, 2396160u,
    2920448u, 3444736u, 3969024u, 4493312u, 5017600u, 5541888u,
    6066176u, 6590464u };
static const uint32_t kMaskH[NLEV] = {
    4095u, 32767u, 262143u, 524287u, 524287u, 524287u, 524287u, 524287u,
    524287u, 524287u, 524287u, 524287u, 524287u, 524287u, 524287u, 524287u };
static const float kScaleH[NLEV] = {
    15.f, 31.f, 63.f, 127.f, 255.f, 511.f, 1023.f, 2047.f,
    4095.f, 8191.f, 16383.f, 32767.f, 65535.f, 131071.f, 262143.f, 524287.f };

__constant__ uint32_t dOff[NLEV] = {
    0u, 4096u, 36864u, 299008u, 823296u, 1347584u, 1871872u, 2396160u,
    2920448u, 3444736u, 3969024u, 4493312u, 5017600u, 5541888u,
    6066176u, 6590464u };
__constant__ uint32_t dMask[NLEV] = {
    4095u, 32767u, 262143u, 524287u, 524287u, 524287u, 524287u, 524287u,
    524287u, 524287u, 524287u, 524287u, 524287u, 524287u, 524287u, 524287u };
__constant__ float dScale[NLEV] = {
    15.f, 31.f, 63.f, 127.f, 255.f, 511.f, 1023.f, 2047.f,
    4095.f, 8191.f, 16383.f, 32767.f, 65535.f, 131071.f, 262143.f, 524287.f };

__device__ __forceinline__ void encode_point(
    float x, float y, float z, float scale, uint32_t mask, uint32_t off,
    uint32_t rows[8], float ws[8])
{
    constexpr uint32_t P1 = 2654435761u, P2 = 805459861u;
    const float px = __fadd_rn(__fmul_rn(x, scale), 0.5f);
    const float py = __fadd_rn(__fmul_rn(y, scale), 0.5f);
    const float pz = __fadd_rn(__fmul_rn(z, scale), 0.5f);
    const float fx0 = floorf(px), fy0 = floorf(py), fz0 = floorf(pz);
    const uint32_t X0 = (uint32_t)fx0;
    const uint32_t Y0 = (uint32_t)fy0;
    const uint32_t Z0 = (uint32_t)fz0;
    const float fx = px - fx0, fy = py - fy0, fz = pz - fz0;

    const uint32_t hx0 = X0,      hx1 = X0 + 1u;
    const uint32_t hy0 = Y0 * P1, hy1 = hy0 + P1;
    const uint32_t hz0 = Z0 * P2, hz1 = hz0 + P2;

    rows[0] = ((hx0 ^ hy0 ^ hz0) & mask) + off;
    rows[1] = ((hx1 ^ hy0 ^ hz0) & mask) + off;
    rows[2] = ((hx0 ^ hy1 ^ hz0) & mask) + off;
    rows[3] = ((hx1 ^ hy1 ^ hz0) & mask) + off;
    rows[4] = ((hx0 ^ hy0 ^ hz1) & mask) + off;
    rows[5] = ((hx1 ^ hy0 ^ hz1) & mask) + off;
    rows[6] = ((hx0 ^ hy1 ^ hz1) & mask) + off;
    rows[7] = ((hx1 ^ hy1 ^ hz1) & mask) + off;

    const float wx1 = fx, wx0 = 1.0f - fx;
    const float wy1 = fy, wy0 = 1.0f - fy;
    const float wz1 = fz, wz0 = 1.0f - fz;
    const float wy0z0 = wy0 * wz0, wy1z0 = wy1 * wz0;
    const float wy0z1 = wy0 * wz1, wy1z1 = wy1 * wz1;
    ws[0] = wx0 * wy0z0; ws[1] = wx1 * wy0z0;
    ws[2] = wx0 * wy1z0; ws[3] = wx1 * wy1z0;
    ws[4] = wx0 * wy0z1; ws[5] = wx1 * wy0z1;
    ws[6] = wx0 * wy1z1; ws[7] = wx1 * wy1z1;
}

// all levels in one dispatch: blockIdx.y = level; two points per thread
__global__ __launch_bounds__(256, 8) void levels_fused_kernel(
    const float* __restrict__ inp,   // [B,3]
    const float2* __restrict__ etab, // [total_rows]
    float2* __restrict__ slab,       // [NLEV][B]
    int B)
{
    const int lvl = blockIdx.y;
    const float    scale = dScale[lvl];
    const uint32_t mask  = dMask[lvl];
    const uint32_t off   = dOff[lvl];
    float2* __restrict__ lslab = slab + (size_t)lvl * B;

    const int t = blockIdx.x * blockDim.x + threadIdx.x;
    const int half = B >> 1;
    if (t >= half) return;
    const int b0 = t, b1 = t + half;

    const float x0 = (inp[3 * b0 + 0] + 1.0f) * 0.5f;
    const float y0 = (inp[3 * b0 + 1] + 1.0f) * 0.5f;
    const float z0 = (inp[3 * b0 + 2] + 1.0f) * 0.5f;
    const float x1 = (inp[3 * b1 + 0] + 1.0f) * 0.5f;
    const float y1 = (inp[3 * b1 + 1] + 1.0f) * 0.5f;
    const float z1 = (inp[3 * b1 + 2] + 1.0f) * 0.5f;

    uint32_t r0[8], r1[8];
    float w0[8], w1[8];
    encode_point(x0, y0, z0, scale, mask, off, r0, w0);
    encode_point(x1, y1, z1, scale, mask, off, r1, w1);

    // issue all 16 gathers before consuming
    float2 e0[8], e1[8];
    #pragma unroll
    for (int c = 0; c < 8; ++c) e0[c] = etab[r0[c]];
    #pragma unroll
    for (int c = 0; c < 8; ++c) e1[c] = etab[r1[c]];

    float a0x = 0.f, a0y = 0.f, a1x = 0.f, a1y = 0.f;
    #pragma unroll
    for (int c = 0; c < 8; ++c) {
        a0x = fmaf(w0[c], e0[c].x, a0x);
        a0y = fmaf(w0[c], e0[c].y, a0y);
        a1x = fmaf(w1[c], e1[c].x, a1x);
        a1y = fmaf(w1[c], e1[c].y, a1y);
    }
    lslab[b0] = make_float2(a0x, a0y);
    lslab[b1] = make_float2(a1x, a1y);
}

// ws [L][B] float2 (level-major) -> out [B][8] float4 (level-interleaved)
// chunk-per-thread: thread g writes exactly one float4 (fully coalesced);
// reads are 8-lane x 64B segments (full line utilization).
__global__ __launch_bounds__(256) void interleave_kernel(
    const float2* __restrict__ ws, float4* __restrict__ out, int B)
{
    const int g = blockIdx.x * blockDim.x + threadIdx.x;
    if (g >= B * 8) return;
    const int p = g >> 3;        // point
    const int c = g & 7;         // float4 chunk = levels (2c, 2c+1)
    const float2 v0 = ws[(size_t)(2 * c)     * B + p];
    const float2 v1 = ws[(size_t)(2 * c + 1) * B + p];
    out[g] = make_float4(v0.x, v0.y, v1.x, v1.y);
}

// ---------------- fallback: round-1 flat kernel (proven correct) -----------
__global__ __launch_bounds__(256) void grid_encode_flat(
    const float* __restrict__ inp, const float* __restrict__ emb,
    float* __restrict__ out, int B)
{
    const int b = blockIdx.x * blockDim.x + threadIdx.x;
    if (b >= B) return;
    const float x = (inp[3 * b + 0] + 1.0f) * 0.5f;
    const float y = (inp[3 * b + 1] + 1.0f) * 0.5f;
    const float z = (inp[3 * b + 2] + 1.0f) * 0.5f;
    const float2* etab = (const float2*)emb;
    float res[2 * NLEV];
    #pragma unroll
    for (int l = 0; l < NLEV; ++l) {
        uint32_t rows[8]; float wts[8];
        encode_point(x, y, z, dScale[l], dMask[l], dOff[l], rows, wts);
        float2 e[8];
        #pragma unroll
        for (int c = 0; c < 8; ++c) e[c] = etab[rows[c]];
        float ax = 0.f, ay = 0.f;
        #pragma unroll
        for (int c = 0; c < 8; ++c) { ax = fmaf(wts[c], e[c].x, ax); ay = fmaf(wts[c], e[c].y, ay); }
        res[2 * l + 0] = ax; res[2 * l + 1] = ay;
    }
    float4* o4 = (float4*)(out + (size_t)b * (2 * NLEV));
    #pragma unroll
    for (int k = 0; k < 8; ++k)
        o4[k] = make_float4(res[4 * k + 0], res[4 * k + 1], res[4 * k + 2], res[4 * k + 3]);
}

extern "C" void kernel_launch(void* const* d_in, const int* in_sizes, int n_in,
                              void* d_out, int out_size, void* d_ws, size_t ws_size,
                              hipStream_t stream) {
    const float* inp = (const float*)d_in[0];   // [B,3] float32
    const float* emb = (const float*)d_in[1];   // [total_rows,2] float32
    float* out = (float*)d_out;                 // [B,32] float32
    const int B = in_sizes[0] / 3;

    const size_t need = (size_t)B * NLEV * 2 * sizeof(float);
    if (ws_size >= need && (B & 1) == 0) {
        float2* ws = (float2*)d_ws;
        const float2* etab = (const float2*)emb;
        const int half = B >> 1;
        dim3 gridL((half + 255) / 256, NLEV);
        levels_fused_kernel<<<gridL, 256, 0, stream>>>(inp, etab, ws, B);
        const int blkI = (B * 8 + 255) / 256;
        interleave_kernel<<<blkI, 256, 0, stream>>>(ws, (float4*)out, B);
    } else {
        const int blk = (B + 255) / 256;
        grid_encode_flat<<<blk, 256, 0, stream>>>(inp, emb, out, B);
    }
}